// Round 2
// baseline (136.577 us; speedup 1.0000x reference)
//
#include <hip/hip_runtime.h>
#include <hip/hip_bf16.h>

// CriticREM: out = relu(relu([state|action]W1^T+b1)W2^T+b2) @ Wc^T + bc
//   Wc = sum_h alpha_h * Wh[h], bc = sum_h alpha_h * bh[h]
// B=65536, IN=128, HID=256, NUM_HEADS=200, OUT=1
//
// R2: direct global A-frag loads for x (no xs LDS stage, no first barrier);
//     H1_PITCH=260 so epilogue ds_write_b16 row-stride = 130 dw ≡ 2 (mod 32)
//     -> each write instr hits 32 distinct banks (was 4-way conflict at 264);
//     LDS 53KB->35KB => 4 blocks/CU.

#define B_TOTAL 65536
#define SDIM 96
#define ADIM 32
#define IN_F 128
#define HID 256
#define NHEADS 200
#define BM 64           // batch rows per block
#define H1_PITCH 260    // 256 + 4 bf16 pad (row stride 520B = 130 dw == 2 mod 32)

typedef __bf16 bf16;
typedef __attribute__((ext_vector_type(8))) __bf16 bf16x8;
typedef __attribute__((ext_vector_type(4))) float f32x4;

// ---- prep: W1,W2 -> bf16 in ws; collapse heads: Wc[256], bc (fp32) ----
__global__ void prep_kernel(const float* __restrict__ W1, const float* __restrict__ W2,
                            const float* __restrict__ alphas, const float* __restrict__ Wh,
                            const float* __restrict__ bh,
                            bf16* __restrict__ W1bf, bf16* __restrict__ W2bf,
                            float* __restrict__ Wc) {
    int tid = blockIdx.x * blockDim.x + threadIdx.x;
    if (tid < IN_F * HID) W1bf[tid] = (bf16)W1[tid];
    if (tid < HID * HID)  W2bf[tid] = (bf16)W2[tid];
    if (tid < HID) {
        float acc = 0.f;
        #pragma unroll 8
        for (int h = 0; h < NHEADS; ++h) acc += alphas[h] * Wh[h * HID + tid];
        Wc[tid] = acc;
    }
    if (tid == HID) {
        float acc = 0.f;
        for (int h = 0; h < NHEADS; ++h) acc += alphas[h] * bh[h];
        Wc[HID] = acc;   // bc
    }
}

// ---- main fused kernel: 256 threads (4 waves), 64 rows per block ----
__global__ __launch_bounds__(256, 4) void critic_kernel(
        const float* __restrict__ state, const float* __restrict__ action,
        const float* __restrict__ b1, const float* __restrict__ b2,
        const bf16* __restrict__ W1bf, const bf16* __restrict__ W2bf,
        const float* __restrict__ Wc, float* __restrict__ out) {

    __shared__ bf16 h1s[BM * H1_PITCH];    // 33280 B
    __shared__ float sWc[HID];             // 1024 B
    __shared__ float sPart[4][BM];         // 1024 B

    const int tid  = threadIdx.x;
    const int wave = tid >> 6;
    const int lane = tid & 63;
    const int q    = lane >> 4;     // 0..3 (k-quad / row-quad in MFMA layouts)
    const int ln   = lane & 15;     // 0..15
    const int colw = wave * 64;     // this wave's output-column slice
    const int row0 = blockIdx.x * BM;

    // stage Wc (head-collapsed weight vector); consumed after the h1 barrier
    sWc[tid] = Wc[tid];

    // ---- GEMM1: h1[64,256] = relu(x @ W1^T + b1); wave owns cols [colw,colw+64) ----
    // A-frags loaded DIRECTLY from global: lane (q,ln) needs x[row=mt*16+ln][k0..k0+7],
    // k0 = ks*32+q*8. ks<3 -> state cols, ks==3 -> action cols. 32B contiguous fp32.
    f32x4 acc[4][4];
    #pragma unroll
    for (int mt = 0; mt < 4; ++mt)
        #pragma unroll
        for (int nt = 0; nt < 4; ++nt)
            acc[mt][nt] = (f32x4){0.f, 0.f, 0.f, 0.f};

    #pragma unroll
    for (int ks = 0; ks < 4; ++ks) {        // K = 128 = 4 x 32
        const int k0 = ks * 32 + q * 8;
        bf16x8 a[4], b[4];
        #pragma unroll
        for (int mt = 0; mt < 4; ++mt) {
            const size_t row = row0 + mt * 16 + ln;
            const float* src = (ks < 3) ? (state  + row * SDIM + k0)
                                        : (action + row * ADIM + q * 8);
            float4 v0 = ((const float4*)src)[0];
            float4 v1 = ((const float4*)src)[1];
            a[mt] = (bf16x8){(bf16)v0.x, (bf16)v0.y, (bf16)v0.z, (bf16)v0.w,
                             (bf16)v1.x, (bf16)v1.y, (bf16)v1.z, (bf16)v1.w};
        }
        #pragma unroll
        for (int nt = 0; nt < 4; ++nt)
            b[nt] = *(const bf16x8*)&W1bf[(size_t)(colw + nt * 16 + ln) * IN_F + k0];
        #pragma unroll
        for (int mt = 0; mt < 4; ++mt)
            #pragma unroll
            for (int nt = 0; nt < 4; ++nt)
                acc[mt][nt] = __builtin_amdgcn_mfma_f32_16x16x32_bf16(a[mt], b[nt], acc[mt][nt], 0, 0, 0);
    }

    // epilogue 1: bias + relu, write bf16 h1 tile to LDS
    // C/D layout: col = ln, row = q*4 + reg  [m89/m91]
    #pragma unroll
    for (int nt = 0; nt < 4; ++nt) {
        const int n      = colw + nt * 16 + ln;
        const float bias = b1[n];
        #pragma unroll
        for (int mt = 0; mt < 4; ++mt)
            #pragma unroll
            for (int r = 0; r < 4; ++r) {
                float v = acc[mt][nt][r] + bias;
                v = v > 0.f ? v : 0.f;
                h1s[(mt * 16 + q * 4 + r) * H1_PITCH + n] = (bf16)v;
            }
    }
    __syncthreads();

    // ---- GEMM2: h2[64,256] = relu(h1 @ W2^T + b2) ----
    #pragma unroll
    for (int mt = 0; mt < 4; ++mt)
        #pragma unroll
        for (int nt = 0; nt < 4; ++nt)
            acc[mt][nt] = (f32x4){0.f, 0.f, 0.f, 0.f};

    #pragma unroll
    for (int ks = 0; ks < 8; ++ks) {        // K = 256 = 8 x 32
        const int k0 = ks * 32 + q * 8;
        bf16x8 a[4], b[4];
        #pragma unroll
        for (int mt = 0; mt < 4; ++mt)
            a[mt] = *(const bf16x8*)&h1s[(mt * 16 + ln) * H1_PITCH + k0];
        #pragma unroll
        for (int nt = 0; nt < 4; ++nt)
            b[nt] = *(const bf16x8*)&W2bf[(size_t)(colw + nt * 16 + ln) * HID + k0];
        #pragma unroll
        for (int mt = 0; mt < 4; ++mt)
            #pragma unroll
            for (int nt = 0; nt < 4; ++nt)
                acc[mt][nt] = __builtin_amdgcn_mfma_f32_16x16x32_bf16(a[mt], b[nt], acc[mt][nt], 0, 0, 0);
    }

    // epilogue 2: bias + relu + dot with Wc, all in-register
    float partial[4][4];
    #pragma unroll
    for (int mt = 0; mt < 4; ++mt)
        #pragma unroll
        for (int r = 0; r < 4; ++r)
            partial[mt][r] = 0.f;

    #pragma unroll
    for (int nt = 0; nt < 4; ++nt) {
        const int n      = colw + nt * 16 + ln;
        const float bias = b2[n];
        const float wc   = sWc[n];
        #pragma unroll
        for (int mt = 0; mt < 4; ++mt)
            #pragma unroll
            for (int r = 0; r < 4; ++r) {
                float v = acc[mt][nt][r] + bias;
                v = v > 0.f ? v : 0.f;
                partial[mt][r] += v * wc;
            }
    }

    // reduce over the 16 lanes (ln dim) that share rows
    #pragma unroll
    for (int off = 1; off < 16; off <<= 1)
        #pragma unroll
        for (int mt = 0; mt < 4; ++mt)
            #pragma unroll
            for (int r = 0; r < 4; ++r)
                partial[mt][r] += __shfl_xor(partial[mt][r], off, 64);

    if (ln == 0) {
        #pragma unroll
        for (int mt = 0; mt < 4; ++mt)
            #pragma unroll
            for (int r = 0; r < 4; ++r)
                sPart[wave][mt * 16 + q * 4 + r] = partial[mt][r];
    }
    __syncthreads();

    // combine the 4 wave column-slices + bc, write out
    if (tid < BM) {
        float v = sPart[0][tid] + sPart[1][tid] + sPart[2][tid] + sPart[3][tid] + Wc[HID];
        out[row0 + tid] = v;
    }
}

extern "C" void kernel_launch(void* const* d_in, const int* in_sizes, int n_in,
                              void* d_out, int out_size, void* d_ws, size_t ws_size,
                              hipStream_t stream) {
    const float* state  = (const float*)d_in[0];
    const float* action = (const float*)d_in[1];
    const float* alphas = (const float*)d_in[2];
    const float* W1     = (const float*)d_in[3];
    const float* b1     = (const float*)d_in[4];
    const float* W2     = (const float*)d_in[5];
    const float* b2     = (const float*)d_in[6];
    const float* Wh     = (const float*)d_in[7];
    const float* bh     = (const float*)d_in[8];
    float* out = (float*)d_out;

    bf16*  W1bf = (bf16*)d_ws;                                  // 65536 B
    bf16*  W2bf = (bf16*)((char*)d_ws + 65536);                 // 131072 B
    float* Wc   = (float*)((char*)d_ws + 65536 + 131072);       // 257 * 4 B

    prep_kernel<<<256, 256, 0, stream>>>(W1, W2, alphas, Wh, bh, W1bf, W2bf, Wc);
    critic_kernel<<<B_TOTAL / BM, 256, 0, stream>>>(state, action, b1, b2, W1bf, W2bf, Wc, out);
}

// Round 3
// 117.414 us; speedup vs baseline: 1.1632x; 1.1632x over previous
//
#include <hip/hip_runtime.h>
#include <hip/hip_bf16.h>

// CriticREM: out = relu(relu([state|action]W1^T+b1)W2^T+b2) @ Wc^T + bc
//   Wc = sum_h alpha_h * Wh[h], bc = sum_h alpha_h * bh[h]
// B=65536, IN=128, HID=256, NUM_HEADS=200, OUT=1
//
// R3: weight-REGISTER-resident persistent blocks.
//   grid=256 (1 block/CU), launch_bounds(256,1) -> 512 VGPR budget.
//   Each wave: W1 slice 64 VGPR + W2 slice 128 VGPR + acc 64 VGPR, loaded ONCE.
//   Block loops 4 row-tiles of 64; next x-tile prefetched into regs during MFMA.
//   L2 weight traffic 196MB -> 48MB; no per-tile global loads on critical path.
//   xs pitch 136 (16B-aligned rows), h1 pitch 260 (measured 0 LDS conflicts in R2).

#define B_TOTAL 65536
#define SDIM 96
#define ADIM 32
#define IN_F 128
#define HID 256
#define NHEADS 200
#define BM 64           // batch rows per tile
#define NTILES 4        // tiles per block
#define XS_PITCH 136    // 272B row stride: 16B-aligned, 2-way-only bank alias (free)
#define H1_PITCH 260    // 520B row stride == 2 mod 32 dw: measured 0 conflicts (R2)

typedef __bf16 bf16;
typedef __attribute__((ext_vector_type(8))) __bf16 bf16x8;
typedef __attribute__((ext_vector_type(4))) float f32x4;

// ---- prep: W1,W2 -> bf16 in ws; collapse heads: Wc[256], bc (fp32) ----
__global__ void prep_kernel(const float* __restrict__ W1, const float* __restrict__ W2,
                            const float* __restrict__ alphas, const float* __restrict__ Wh,
                            const float* __restrict__ bh,
                            bf16* __restrict__ W1bf, bf16* __restrict__ W2bf,
                            float* __restrict__ Wc) {
    int tid = blockIdx.x * blockDim.x + threadIdx.x;
    if (tid < IN_F * HID) W1bf[tid] = (bf16)W1[tid];
    if (tid < HID * HID)  W2bf[tid] = (bf16)W2[tid];
    if (tid < HID) {
        float acc = 0.f;
        #pragma unroll 8
        for (int h = 0; h < NHEADS; ++h) acc += alphas[h] * Wh[h * HID + tid];
        Wc[tid] = acc;
    }
    if (tid == HID) {
        float acc = 0.f;
        for (int h = 0; h < NHEADS; ++h) acc += alphas[h] * bh[h];
        Wc[HID] = acc;   // bc
    }
}

// ---- main fused kernel: 256 threads (4 waves), persistent over 4 tiles ----
__global__ __launch_bounds__(256, 1) void critic_kernel(
        const float* __restrict__ state, const float* __restrict__ action,
        const float* __restrict__ b1, const float* __restrict__ b2,
        const bf16* __restrict__ W1bf, const bf16* __restrict__ W2bf,
        const float* __restrict__ Wc, float* __restrict__ out) {

    __shared__ bf16 xs[BM * XS_PITCH];     // 17408 B
    __shared__ bf16 h1s[BM * H1_PITCH];    // 33280 B
    __shared__ float sPart[4][BM];         // 1024 B

    const int tid  = threadIdx.x;
    const int wave = tid >> 6;
    const int lane = tid & 63;
    const int q    = lane >> 4;     // 0..3
    const int ln   = lane & 15;     // 0..15
    const int colw = wave * 64;     // this wave's output-column slice
    const int brow0 = blockIdx.x * (BM * NTILES);

    // ---- preamble: weights into REGISTERS, once per block ----
    bf16x8 w1f[4][4];   // [ks][nt]  64 VGPRs
    #pragma unroll
    for (int ks = 0; ks < 4; ++ks)
        #pragma unroll
        for (int nt = 0; nt < 4; ++nt)
            w1f[ks][nt] = *(const bf16x8*)&W1bf[(size_t)(colw + nt * 16 + ln) * IN_F + ks * 32 + q * 8];

    bf16x8 w2f[8][4];   // [ks][nt]  128 VGPRs
    #pragma unroll
    for (int ks = 0; ks < 8; ++ks)
        #pragma unroll
        for (int nt = 0; nt < 4; ++nt)
            w2f[ks][nt] = *(const bf16x8*)&W2bf[(size_t)(colw + nt * 16 + ln) * HID + ks * 32 + q * 8];

    // per-lane bias / head-vector values (col n = colw + nt*16 + ln)
    float b1v[4], b2v[4], wcv[4];
    #pragma unroll
    for (int nt = 0; nt < 4; ++nt) {
        const int n = colw + nt * 16 + ln;
        b1v[nt] = b1[n];
        b2v[nt] = b2[n];
        wcv[nt] = Wc[n];
    }
    const float bc = Wc[HID];

    // ---- x prefetch for tile 0 ----
    // thread handles 4 chunks of 8 cols: idx = tid + i*256, r = idx>>4, c8 = idx&15
    float4 px[4][2];
    {
        const int row0 = brow0;
        #pragma unroll
        for (int i = 0; i < 4; ++i) {
            const int idx = tid + i * 256;
            const int r   = idx >> 4;
            const int c8  = idx & 15;
            const float* src = (c8 < 12) ? (state  + (size_t)(row0 + r) * SDIM + c8 * 8)
                                         : (action + (size_t)(row0 + r) * ADIM + (c8 - 12) * 8);
            px[i][0] = ((const float4*)src)[0];
            px[i][1] = ((const float4*)src)[1];
        }
    }

    for (int t = 0; t < NTILES; ++t) {
        const int row0 = brow0 + t * BM;

        // stage x tile (convert fp32->bf16, write LDS)
        #pragma unroll
        for (int i = 0; i < 4; ++i) {
            const int idx = tid + i * 256;
            const int r   = idx >> 4;
            const int c8  = idx & 15;
            bf16x8 v = (bf16x8){(bf16)px[i][0].x, (bf16)px[i][0].y, (bf16)px[i][0].z, (bf16)px[i][0].w,
                                (bf16)px[i][1].x, (bf16)px[i][1].y, (bf16)px[i][1].z, (bf16)px[i][1].w};
            *(bf16x8*)&xs[r * XS_PITCH + c8 * 8] = v;
        }
        __syncthreads();

        // prefetch NEXT tile's x while this tile's MFMAs run
        if (t + 1 < NTILES) {
            const int nrow0 = row0 + BM;
            #pragma unroll
            for (int i = 0; i < 4; ++i) {
                const int idx = tid + i * 256;
                const int r   = idx >> 4;
                const int c8  = idx & 15;
                const float* src = (c8 < 12) ? (state  + (size_t)(nrow0 + r) * SDIM + c8 * 8)
                                             : (action + (size_t)(nrow0 + r) * ADIM + (c8 - 12) * 8);
                px[i][0] = ((const float4*)src)[0];
                px[i][1] = ((const float4*)src)[1];
            }
        }

        // ---- GEMM1: h1 = relu(x @ W1^T + b1) ----
        f32x4 acc[4][4];
        #pragma unroll
        for (int mt = 0; mt < 4; ++mt)
            #pragma unroll
            for (int nt = 0; nt < 4; ++nt)
                acc[mt][nt] = (f32x4){0.f, 0.f, 0.f, 0.f};

        #pragma unroll
        for (int ks = 0; ks < 4; ++ks) {
            const int k0 = ks * 32 + q * 8;
            bf16x8 a[4];
            #pragma unroll
            for (int mt = 0; mt < 4; ++mt)
                a[mt] = *(const bf16x8*)&xs[(mt * 16 + ln) * XS_PITCH + k0];
            #pragma unroll
            for (int mt = 0; mt < 4; ++mt)
                #pragma unroll
                for (int nt = 0; nt < 4; ++nt)
                    acc[mt][nt] = __builtin_amdgcn_mfma_f32_16x16x32_bf16(a[mt], w1f[ks][nt], acc[mt][nt], 0, 0, 0);
        }

        // epilogue 1: bias+relu -> h1s (C/D layout: col=ln, row=q*4+r)
        #pragma unroll
        for (int nt = 0; nt < 4; ++nt) {
            const int n = colw + nt * 16 + ln;
            #pragma unroll
            for (int mt = 0; mt < 4; ++mt)
                #pragma unroll
                for (int r = 0; r < 4; ++r) {
                    float v = acc[mt][nt][r] + b1v[nt];
                    v = v > 0.f ? v : 0.f;
                    h1s[(mt * 16 + q * 4 + r) * H1_PITCH + n] = (bf16)v;
                }
        }
        __syncthreads();

        // ---- GEMM2: h2 = relu(h1 @ W2^T + b2) ----
        #pragma unroll
        for (int mt = 0; mt < 4; ++mt)
            #pragma unroll
            for (int nt = 0; nt < 4; ++nt)
                acc[mt][nt] = (f32x4){0.f, 0.f, 0.f, 0.f};

        #pragma unroll
        for (int ks = 0; ks < 8; ++ks) {
            const int k0 = ks * 32 + q * 8;
            bf16x8 a[4];
            #pragma unroll
            for (int mt = 0; mt < 4; ++mt)
                a[mt] = *(const bf16x8*)&h1s[(mt * 16 + ln) * H1_PITCH + k0];
            #pragma unroll
            for (int mt = 0; mt < 4; ++mt)
                #pragma unroll
                for (int nt = 0; nt < 4; ++nt)
                    acc[mt][nt] = __builtin_amdgcn_mfma_f32_16x16x32_bf16(a[mt], w2f[ks][nt], acc[mt][nt], 0, 0, 0);
        }

        // epilogue 2: bias+relu, dot with Wc, shfl-reduce over ln
        float partial[4][4];
        #pragma unroll
        for (int mt = 0; mt < 4; ++mt)
            #pragma unroll
            for (int r = 0; r < 4; ++r)
                partial[mt][r] = 0.f;

        #pragma unroll
        for (int nt = 0; nt < 4; ++nt) {
            #pragma unroll
            for (int mt = 0; mt < 4; ++mt)
                #pragma unroll
                for (int r = 0; r < 4; ++r) {
                    float v = acc[mt][nt][r] + b2v[nt];
                    v = v > 0.f ? v : 0.f;
                    partial[mt][r] += v * wcv[nt];
                }
        }

        #pragma unroll
        for (int off = 1; off < 16; off <<= 1)
            #pragma unroll
            for (int mt = 0; mt < 4; ++mt)
                #pragma unroll
                for (int r = 0; r < 4; ++r)
                    partial[mt][r] += __shfl_xor(partial[mt][r], off, 64);

        if (ln == 0) {
            #pragma unroll
            for (int mt = 0; mt < 4; ++mt)
                #pragma unroll
                for (int r = 0; r < 4; ++r)
                    sPart[wave][mt * 16 + q * 4 + r] = partial[mt][r];
        }
        __syncthreads();

        if (tid < BM) {
            float v = sPart[0][tid] + sPart[1][tid] + sPart[2][tid] + sPart[3][tid] + bc;
            out[row0 + tid] = v;
        }
        // NOTE: next iteration's xs ds_write is safe: the barrier above guarantees
        // all GEMM1/GEMM2 LDS reads of this tile completed.
    }
}

extern "C" void kernel_launch(void* const* d_in, const int* in_sizes, int n_in,
                              void* d_out, int out_size, void* d_ws, size_t ws_size,
                              hipStream_t stream) {
    const float* state  = (const float*)d_in[0];
    const float* action = (const float*)d_in[1];
    const float* alphas = (const float*)d_in[2];
    const float* W1     = (const float*)d_in[3];
    const float* b1     = (const float*)d_in[4];
    const float* W2     = (const float*)d_in[5];
    const float* b2     = (const float*)d_in[6];
    const float* Wh     = (const float*)d_in[7];
    const float* bh     = (const float*)d_in[8];
    float* out = (float*)d_out;

    bf16*  W1bf = (bf16*)d_ws;                                  // 65536 B
    bf16*  W2bf = (bf16*)((char*)d_ws + 65536);                 // 131072 B
    float* Wc   = (float*)((char*)d_ws + 65536 + 131072);       // 257 * 4 B

    prep_kernel<<<256, 256, 0, stream>>>(W1, W2, alphas, Wh, bh, W1bf, W2bf, Wc);
    critic_kernel<<<B_TOTAL / (BM * NTILES), 256, 0, stream>>>(state, action, b1, b2, W1bf, W2bf, Wc, out);
}